// Round 1
// baseline (1172.241 us; speedup 1.0000x reference)
//
#include <hip/hip_runtime.h>

typedef float f32x4 __attribute__((ext_vector_type(4)));
typedef short bf16x8 __attribute__((ext_vector_type(8)));

#define SLOPE 0.01f

__device__ __forceinline__ short f2bf(float f) {
    unsigned int u = __float_as_uint(f);
    unsigned int r = (u + 0x7fffu + ((u >> 16) & 1u)) >> 16;
    return (short)r;
}

// ---- W -> MFMA fragment layout staging -------------------------------------
// Fragment layout: flat bf16 index ((ntile*KSTEPS + ks)*64 + lane)*8 + j
// holds W[k][n] with k = ks*32 + (lane>>4)*8 + j, n = ntile*16 + (lane&15).
__global__ void stage_w(const float* __restrict__ W1, const float* __restrict__ W2,
                        short* __restrict__ wf1, short* __restrict__ wf2) {
    int t = blockIdx.x * blockDim.x + threadIdx.x;
    if (t < 4096) {                       // W1: 8 ntiles x 8 ksteps x 64 lanes
        int ntile = t >> 9;
        int ks = (t >> 6) & 7;
        int lane = t & 63;
        int h = lane >> 4, c = lane & 15;
#pragma unroll
        for (int j = 0; j < 8; j++) {
            int k = ks * 32 + h * 8 + j;
            wf1[t * 8 + j] = f2bf(W1[k * 128 + ntile * 16 + c]);
        }
    } else if (t < 6144) {                // W2: 8 ntiles x 4 ksteps x 64 lanes
        int s = t - 4096;
        int ntile = s >> 8;
        int ks = (s >> 6) & 3;
        int lane = s & 63;
        int h = lane >> 4, c = lane & 15;
#pragma unroll
        for (int j = 0; j < 8; j++) {
            int k = ks * 32 + h * 8 + j;
            wf2[s * 8 + j] = f2bf(W2[k * 128 + ntile * 16 + c]);
        }
    }
}

// ---- degree + inv-sqrt ------------------------------------------------------
__global__ void k_deg(const int* __restrict__ col, const float* __restrict__ w,
                      float* __restrict__ deg, int E) {
    for (int i = blockIdx.x * blockDim.x + threadIdx.x; i < E; i += gridDim.x * blockDim.x)
        atomicAdd(&deg[col[i]], w[i]);
}

__global__ void k_dis(const float* __restrict__ deg, float* __restrict__ dis, int N) {
    int i = blockIdx.x * blockDim.x + threadIdx.x;
    if (i < N) {
        float d = deg[i];
        dis[i] = d > 0.f ? rsqrtf(d) : 0.f;
    }
}

// ---- MFMA GEMM: out[M][128] = act(A[M][K]) @ W (fragment-staged) ------------
template <int KSTEPS, bool ACT>
__global__ __launch_bounds__(256) void k_gemm(const float* __restrict__ A,
                                              const short* __restrict__ Wf,
                                              const float* __restrict__ bias,
                                              float* __restrict__ out, int M) {
    const int lane = threadIdx.x & 63;
    const int wid = threadIdx.x >> 6;
    const int rowbase = blockIdx.x * 64 + wid * 16;
    const int h = lane >> 4, c = lane & 15;
    int arow = rowbase + c;
    if (arow >= M) arow = M - 1;
    const int K = KSTEPS * 32;

    bf16x8 afrag[KSTEPS];
    const float* arp = A + (long)arow * K + h * 8;
#pragma unroll
    for (int ks = 0; ks < KSTEPS; ks++) {
        float4 a0 = *(const float4*)(arp + ks * 32);
        float4 a1 = *(const float4*)(arp + ks * 32 + 4);
        float v[8] = {a0.x, a0.y, a0.z, a0.w, a1.x, a1.y, a1.z, a1.w};
        if (ACT) {
            const float* bp = bias + ks * 32 + h * 8;
            float4 b0 = *(const float4*)(bp);
            float4 b1v = *(const float4*)(bp + 4);
            float bv[8] = {b0.x, b0.y, b0.z, b0.w, b1v.x, b1v.y, b1v.z, b1v.w};
#pragma unroll
            for (int j = 0; j < 8; j++) {
                float t = v[j] + bv[j];
                v[j] = t < 0.f ? SLOPE * t : t;
            }
        }
        bf16x8 f;
#pragma unroll
        for (int j = 0; j < 8; j++) f[j] = f2bf(v[j]);
        afrag[ks] = f;
    }

    const bf16x8* wf8 = (const bf16x8*)Wf;
#pragma unroll
    for (int nt = 0; nt < 8; nt++) {
        f32x4 acc = {0.f, 0.f, 0.f, 0.f};
#pragma unroll
        for (int ks = 0; ks < KSTEPS; ks++)
            acc = __builtin_amdgcn_mfma_f32_16x16x32_bf16(afrag[ks], wf8[(nt * KSTEPS + ks) * 64 + lane], acc, 0, 0, 0);
        int orow = rowbase + h * 4;
#pragma unroll
        for (int i = 0; i < 4; i++)
            if (orow + i < M) out[(long)(orow + i) * 128 + nt * 16 + c] = acc[i];
    }
}

// ---- edge scatter: agg[col] += norm * h[row] --------------------------------
__global__ __launch_bounds__(256) void k_scatter(const int* __restrict__ ei, const float* __restrict__ w,
                                                 const float* __restrict__ dis, const float* __restrict__ hbuf,
                                                 float* __restrict__ agg, int E) {
    const int lane = threadIdx.x & 63;
    int wv = (blockIdx.x * blockDim.x + threadIdx.x) >> 6;
    const int nw = (gridDim.x * blockDim.x) >> 6;
    for (int e = wv; e < E; e += nw) {
        int r = ei[e];
        int cn = ei[E + e];
        float nrm = dis[r] * w[e] * dis[cn];
        float2 hv = ((const float2*)hbuf)[(long)r * 64 + lane];
        atomicAdd(&agg[(long)cn * 128 + lane * 2], nrm * hv.x);
        atomicAdd(&agg[(long)cn * 128 + lane * 2 + 1], nrm * hv.y);
    }
}

// ---- pool: per-graph mean of leaky(agg + b2), batch is sorted ---------------
__global__ __launch_bounds__(128) void k_pool(const float* __restrict__ agg, const float* __restrict__ b2,
                                              const int* __restrict__ batch, float* __restrict__ sums,
                                              float* __restrict__ cnts, int N) {
    int n0 = blockIdx.x * 128;
    if (n0 >= N) return;
    int f = threadIdx.x;
    int end = min(n0 + 128, N);
    int curg = batch[n0];
    float acc = 0.f;
    int run = 0;
    float b = b2[f];
    for (int n = n0; n < end; n++) {
        int g = batch[n];
        if (g != curg) {
            atomicAdd(&sums[curg * 128 + f], acc);
            if (f == 0) atomicAdd(&cnts[curg], (float)run);
            acc = 0.f; run = 0; curg = g;
        }
        float v = agg[(long)n * 128 + f] + b;
        v = v < 0.f ? SLOPE * v : v;
        acc += v;
        run++;
    }
    atomicAdd(&sums[curg * 128 + f], acc);
    if (f == 0) atomicAdd(&cnts[curg], (float)run);
}

// ---- classifier + log_softmax ----------------------------------------------
__global__ void k_final(const float* __restrict__ sums, const float* __restrict__ cnts,
                        const float* __restrict__ Wl, const float* __restrict__ bl,
                        float* __restrict__ out, int G) {
    int g = blockIdx.x * blockDim.x + threadIdx.x;
    if (g >= G) return;
    float inv = 1.f / fmaxf(cnts[g], 1.f);
    float l[10];
#pragma unroll
    for (int c = 0; c < 10; c++) l[c] = bl[c];
    for (int k = 0; k < 128; k++) {
        float p = sums[g * 128 + k] * inv;
#pragma unroll
        for (int c = 0; c < 10; c++) l[c] += p * Wl[k * 10 + c];
    }
    float m = l[0];
#pragma unroll
    for (int c = 1; c < 10; c++) m = fmaxf(m, l[c]);
    float s = 0.f;
#pragma unroll
    for (int c = 0; c < 10; c++) s += expf(l[c] - m);
    float lse = m + logf(s);
#pragma unroll
    for (int c = 0; c < 10; c++) out[g * 10 + c] = l[c] - lse;
}

extern "C" void kernel_launch(void* const* d_in, const int* in_sizes, int n_in,
                              void* d_out, int out_size, void* d_ws, size_t ws_size,
                              hipStream_t stream) {
    const float* x  = (const float*)d_in[0];
    const int*   ei = (const int*)d_in[1];
    const float* ew = (const float*)d_in[2];
    const int*   batch = (const int*)d_in[3];
    const float* W1 = (const float*)d_in[4];
    const float* b1 = (const float*)d_in[5];
    const float* W2 = (const float*)d_in[6];
    const float* b2 = (const float*)d_in[7];
    const float* Wl = (const float*)d_in[8];
    const float* bl = (const float*)d_in[9];
    float* out = (float*)d_out;

    const int N = in_sizes[0] / 256;
    const int E = in_sizes[2];
    const int G = out_size / 10;

    char* ws = (char*)d_ws;
    float* deg  = (float*)(ws);                 // 400,000 B
    float* dis  = (float*)(ws + 400384);        // 400,000 B
    float* hbuf = (float*)(ws + 800768);        // 51,200,000 B
    float* agg  = (float*)(ws + 52000768);      // 51,200,000 B
    short* wf1  = (short*)(ws + 103200768);     // 65,536 B
    short* wf2  = (short*)(ws + 103266304);     // 32,768 B
    float* sums = (float*)(ws + 103299072);     // 131,072 B
    float* cnts = (float*)(ws + 103430144);     // 1,024 B

    hipMemsetAsync(deg, 0, (size_t)N * 4, stream);
    hipMemsetAsync(agg, 0, (size_t)N * 128 * 4, stream);
    hipMemsetAsync(sums, 0, (size_t)G * 128 * 4, stream);
    hipMemsetAsync(cnts, 0, (size_t)G * 4, stream);

    stage_w<<<24, 256, 0, stream>>>(W1, W2, wf1, wf2);
    k_deg<<<1024, 256, 0, stream>>>(ei + E, ew, deg, E);
    k_dis<<<(N + 255) / 256, 256, 0, stream>>>(deg, dis, N);

    // layer 1: h = x @ W1 ; agg = scatter(norm * h[row] -> col)
    k_gemm<8, false><<<(N + 63) / 64, 256, 0, stream>>>(x, wf1, nullptr, hbuf, N);
    k_scatter<<<2048, 256, 0, stream>>>(ei, ew, dis, hbuf, agg, E);

    // layer 2: h = leaky(agg + b1) @ W2 ; re-zero agg ; scatter again
    k_gemm<4, true><<<(N + 63) / 64, 256, 0, stream>>>(agg, wf2, b1, hbuf, N);
    hipMemsetAsync(agg, 0, (size_t)N * 128 * 4, stream);
    k_scatter<<<2048, 256, 0, stream>>>(ei, ew, dis, hbuf, agg, E);

    // pool (fused bias+leaky) + classifier + log_softmax
    k_pool<<<(N + 127) / 128, 128, 0, stream>>>(agg, b2, batch, sums, cnts, N);
    k_final<<<1, 256, 0, stream>>>(sums, cnts, Wl, bl, out, G);
}

// Round 2
// 379.039 us; speedup vs baseline: 3.0927x; 3.0927x over previous
//
#include <hip/hip_runtime.h>

typedef float f32x4 __attribute__((ext_vector_type(4)));
typedef short bf16x8 __attribute__((ext_vector_type(8)));

#define SLOPE 0.01f

__device__ __forceinline__ short f2bf(float f) {
    unsigned int u = __float_as_uint(f);
    unsigned int r = (u + 0x7fffu + ((u >> 16) & 1u)) >> 16;
    return (short)r;
}

// ---- W -> MFMA fragment layout staging -------------------------------------
// flat bf16 index ((ntile*KSTEPS + ks)*64 + lane)*8 + j holds W[k][n],
// k = ks*32 + (lane>>4)*8 + j, n = ntile*16 + (lane&15).
__global__ void stage_w(const float* __restrict__ W1, const float* __restrict__ W2,
                        short* __restrict__ wf1, short* __restrict__ wf2) {
    int t = blockIdx.x * blockDim.x + threadIdx.x;
    if (t < 4096) {                       // W1: 8 ntiles x 8 ksteps x 64 lanes
        int ntile = t >> 9;
        int ks = (t >> 6) & 7;
        int lane = t & 63;
        int h = lane >> 4, c = lane & 15;
#pragma unroll
        for (int j = 0; j < 8; j++) {
            int k = ks * 32 + h * 8 + j;
            wf1[t * 8 + j] = f2bf(W1[k * 128 + ntile * 16 + c]);
        }
    } else if (t < 6144) {                // W2: 8 ntiles x 4 ksteps x 64 lanes
        int s = t - 4096;
        int ntile = s >> 8;
        int ks = (s >> 6) & 3;
        int lane = s & 63;
        int h = lane >> 4, c = lane & 15;
#pragma unroll
        for (int j = 0; j < 8; j++) {
            int k = ks * 32 + h * 8 + j;
            wf2[s * 8 + j] = f2bf(W2[k * 128 + ntile * 16 + c]);
        }
    }
}

// ---- histogram: in-degree count + weighted degree ---------------------------
__global__ void k_hist(const int* __restrict__ ei, const float* __restrict__ w,
                       int* __restrict__ cnt, float* __restrict__ deg, int E) {
    for (int i = blockIdx.x * blockDim.x + threadIdx.x; i < E; i += gridDim.x * blockDim.x) {
        int c = ei[E + i];
        atomicAdd(&cnt[c], 1);
        atomicAdd(&deg[c], w[i]);
    }
}

// ---- bucket allocation (wave scan + 1 atomic/wave) + dis = deg^-1/2 --------
__global__ __launch_bounds__(256) void k_alloc(const int* __restrict__ cnt, const float* __restrict__ deg,
                                               float* __restrict__ dis, int* __restrict__ rowstart,
                                               int* __restrict__ cursor, int* __restrict__ gcur, int N) {
    int n = blockIdx.x * blockDim.x + threadIdx.x;
    int lane = threadIdx.x & 63;
    int c = (n < N) ? cnt[n] : 0;
    int v = c;
#pragma unroll
    for (int off = 1; off < 64; off <<= 1) {
        int t = __shfl_up(v, off);
        if (lane >= off) v += t;
    }
    int tot = __shfl(v, 63);
    int base = 0;
    if (lane == 63) base = atomicAdd(gcur, tot);
    base = __shfl(base, 63);
    if (n < N) {
        int rs = base + v - c;       // exclusive within wave
        rowstart[n] = rs;
        cursor[n] = rs;
        float d = deg[n];
        dis[n] = d > 0.f ? rsqrtf(d) : 0.f;
    }
}

// ---- fill CSR buckets: (row, norm) pairs per target node --------------------
__global__ void k_fill(const int* __restrict__ ei, const float* __restrict__ w,
                       const float* __restrict__ dis, int* __restrict__ cursor,
                       uint2* __restrict__ ebuf, int E) {
    for (int i = blockIdx.x * blockDim.x + threadIdx.x; i < E; i += gridDim.x * blockDim.x) {
        int r = ei[i], c = ei[E + i];
        float nrm = dis[r] * w[i] * dis[c];
        int pos = atomicAdd(&cursor[c], 1);
        ebuf[pos] = make_uint2((unsigned)r, __float_as_uint(nrm));
    }
}

// ---- MFMA GEMM: hbuf(bf16)[M][128] = bf16(act(A[M][K]) @ W) -----------------
template <int KSTEPS, bool ACT>
__global__ __launch_bounds__(256) void k_gemm(const float* __restrict__ A,
                                              const short* __restrict__ Wf,
                                              const float* __restrict__ bias,
                                              ushort* __restrict__ out, int M) {
    const int lane = threadIdx.x & 63;
    const int wid = threadIdx.x >> 6;
    const int rowbase = blockIdx.x * 64 + wid * 16;
    const int h = lane >> 4, c = lane & 15;
    int arow = rowbase + c;
    if (arow >= M) arow = M - 1;
    const int K = KSTEPS * 32;

    bf16x8 afrag[KSTEPS];
    const float* arp = A + (long)arow * K + h * 8;
#pragma unroll
    for (int ks = 0; ks < KSTEPS; ks++) {
        float4 a0 = *(const float4*)(arp + ks * 32);
        float4 a1 = *(const float4*)(arp + ks * 32 + 4);
        float v[8] = {a0.x, a0.y, a0.z, a0.w, a1.x, a1.y, a1.z, a1.w};
        if (ACT) {
            const float* bp = bias + ks * 32 + h * 8;
            float4 b0 = *(const float4*)(bp);
            float4 b1v = *(const float4*)(bp + 4);
            float bv[8] = {b0.x, b0.y, b0.z, b0.w, b1v.x, b1v.y, b1v.z, b1v.w};
#pragma unroll
            for (int j = 0; j < 8; j++) {
                float t = v[j] + bv[j];
                v[j] = t < 0.f ? SLOPE * t : t;
            }
        }
        bf16x8 f;
#pragma unroll
        for (int j = 0; j < 8; j++) f[j] = f2bf(v[j]);
        afrag[ks] = f;
    }

    const bf16x8* wf8 = (const bf16x8*)Wf;
#pragma unroll
    for (int nt = 0; nt < 8; nt++) {
        f32x4 acc = {0.f, 0.f, 0.f, 0.f};
#pragma unroll
        for (int ks = 0; ks < KSTEPS; ks++)
            acc = __builtin_amdgcn_mfma_f32_16x16x32_bf16(afrag[ks], wf8[(nt * KSTEPS + ks) * 64 + lane], acc, 0, 0, 0);
        int orow = rowbase + h * 4;
#pragma unroll
        for (int i = 0; i < 4; i++)
            if (orow + i < M) out[(long)(orow + i) * 128 + nt * 16 + c] = (ushort)f2bf(acc[i]);
    }
}

// ---- gather-aggregate: agg[n] = sum over in-edges of nrm * h[row] -----------
__global__ __launch_bounds__(256) void k_agg(const uint2* __restrict__ ebuf, const int* __restrict__ rowstart,
                                             const int* __restrict__ cnt, const unsigned* __restrict__ hbuf,
                                             float* __restrict__ agg, int N) {
    int wv = (blockIdx.x * blockDim.x + threadIdx.x) >> 6;
    int lane = threadIdx.x & 63;
    if (wv >= N) return;
    int s = rowstart[wv];
    int e = s + cnt[wv];
    float ax = 0.f, ay = 0.f;
    for (int i = s; i < e; i++) {
        uint2 p = ebuf[i];                      // broadcast 8B (same addr all lanes)
        float nrm = __uint_as_float(p.y);
        unsigned hv = hbuf[(long)p.x * 64 + lane];  // coalesced 256B row gather
        ax += nrm * __uint_as_float(hv << 16);
        ay += nrm * __uint_as_float(hv & 0xffff0000u);
    }
    float2* o = (float2*)(agg + (long)wv * 128);
    o[lane] = make_float2(ax, ay);
}

// ---- pool: per-graph mean of leaky(agg + b2), batch is sorted ---------------
__global__ __launch_bounds__(128) void k_pool(const float* __restrict__ agg, const float* __restrict__ b2,
                                              const int* __restrict__ batch, float* __restrict__ sums,
                                              float* __restrict__ cnts, int N) {
    int n0 = blockIdx.x * 128;
    if (n0 >= N) return;
    int f = threadIdx.x;
    int end = min(n0 + 128, N);
    int curg = batch[n0];
    float acc = 0.f;
    int run = 0;
    float b = b2[f];
    for (int n = n0; n < end; n++) {
        int g = batch[n];
        if (g != curg) {
            atomicAdd(&sums[curg * 128 + f], acc);
            if (f == 0) atomicAdd(&cnts[curg], (float)run);
            acc = 0.f; run = 0; curg = g;
        }
        float v = agg[(long)n * 128 + f] + b;
        v = v < 0.f ? SLOPE * v : v;
        acc += v;
        run++;
    }
    atomicAdd(&sums[curg * 128 + f], acc);
    if (f == 0) atomicAdd(&cnts[curg], (float)run);
}

// ---- classifier + log_softmax ----------------------------------------------
__global__ void k_final(const float* __restrict__ sums, const float* __restrict__ cnts,
                        const float* __restrict__ Wl, const float* __restrict__ bl,
                        float* __restrict__ out, int G) {
    int g = blockIdx.x * blockDim.x + threadIdx.x;
    if (g >= G) return;
    float inv = 1.f / fmaxf(cnts[g], 1.f);
    float l[10];
#pragma unroll
    for (int c = 0; c < 10; c++) l[c] = bl[c];
    for (int k = 0; k < 128; k++) {
        float p = sums[g * 128 + k] * inv;
#pragma unroll
        for (int c = 0; c < 10; c++) l[c] += p * Wl[k * 10 + c];
    }
    float m = l[0];
#pragma unroll
    for (int c = 1; c < 10; c++) m = fmaxf(m, l[c]);
    float s = 0.f;
#pragma unroll
    for (int c = 0; c < 10; c++) s += expf(l[c] - m);
    float lse = m + logf(s);
#pragma unroll
    for (int c = 0; c < 10; c++) out[g * 10 + c] = l[c] - lse;
}

extern "C" void kernel_launch(void* const* d_in, const int* in_sizes, int n_in,
                              void* d_out, int out_size, void* d_ws, size_t ws_size,
                              hipStream_t stream) {
    const float* x  = (const float*)d_in[0];
    const int*   ei = (const int*)d_in[1];
    const float* ew = (const float*)d_in[2];
    const int*   batch = (const int*)d_in[3];
    const float* W1 = (const float*)d_in[4];
    const float* b1 = (const float*)d_in[5];
    const float* W2 = (const float*)d_in[6];
    const float* b2 = (const float*)d_in[7];
    const float* Wl = (const float*)d_in[8];
    const float* bl = (const float*)d_in[9];
    float* out = (float*)d_out;

    const int N = in_sizes[0] / 256;
    const int E = in_sizes[2];
    const int G = out_size / 10;

    char* ws = (char*)d_ws;
    float*  deg      = (float*)(ws);                  // 400,384
    float*  dis      = (float*)(ws + 400384);         // 400,384
    int*    cnt      = (int*)  (ws + 800768);         // 400,384
    int*    rowstart = (int*)  (ws + 1201152);        // 400,384
    int*    cursor   = (int*)  (ws + 1601536);        // 400,384
    int*    gcur     = (int*)  (ws + 2001920);        // 128
    uint2*  ebuf     = (uint2*)(ws + 2002048);        // 4,800,000
    ushort* hbuf     = (ushort*)(ws + 6802048);       // 25,600,000
    float*  agg      = (float*)(ws + 32402048);       // 51,200,000
    short*  wf1      = (short*)(ws + 83602048);       // 65,536
    short*  wf2      = (short*)(ws + 83667584);       // 32,768
    float*  sums     = (float*)(ws + 83700352);       // 131,072
    float*  cnts     = (float*)(ws + 83831424);       // 1,024

    hipMemsetAsync(deg, 0, (size_t)N * 4, stream);
    hipMemsetAsync(cnt, 0, (size_t)N * 4, stream);
    hipMemsetAsync(gcur, 0, 128, stream);
    hipMemsetAsync(sums, 0, (size_t)G * 128 * 4, stream);
    hipMemsetAsync(cnts, 0, (size_t)G * 4, stream);

    stage_w<<<24, 256, 0, stream>>>(W1, W2, wf1, wf2);
    k_hist<<<1024, 256, 0, stream>>>(ei, ew, cnt, deg, E);
    k_alloc<<<(N + 255) / 256, 256, 0, stream>>>(cnt, deg, dis, rowstart, cursor, gcur, N);
    k_fill<<<2048, 256, 0, stream>>>(ei, ew, dis, cursor, ebuf, E);

    // layer 1: h = bf16(x @ W1) ; agg = gather-sum(nrm * h[row])
    k_gemm<8, false><<<(N + 63) / 64, 256, 0, stream>>>(x, wf1, nullptr, hbuf, N);
    k_agg<<<(N + 3) / 4, 256, 0, stream>>>(ebuf, rowstart, cnt, (const unsigned*)hbuf, agg, N);

    // layer 2: h = bf16(leaky(agg + b1) @ W2) ; aggregate again
    k_gemm<4, true><<<(N + 63) / 64, 256, 0, stream>>>(agg, wf2, b1, hbuf, N);
    k_agg<<<(N + 3) / 4, 256, 0, stream>>>(ebuf, rowstart, cnt, (const unsigned*)hbuf, agg, N);

    // pool (fused bias+leaky) + classifier + log_softmax
    k_pool<<<(N + 127) / 128, 128, 0, stream>>>(agg, b2, batch, sums, cnts, N);
    k_final<<<1, 256, 0, stream>>>(sums, cnts, Wl, bl, out, G);
}

// Round 3
// 285.576 us; speedup vs baseline: 4.1048x; 1.3273x over previous
//
#include <hip/hip_runtime.h>

typedef float f32x4 __attribute__((ext_vector_type(4)));
typedef short bf16x8 __attribute__((ext_vector_type(8)));

#define SLOPE 0.01f

__device__ __forceinline__ short f2bf(float f) {
    unsigned int u = __float_as_uint(f);
    unsigned int r = (u + 0x7fffu + ((u >> 16) & 1u)) >> 16;
    return (short)r;
}

// ---- W -> MFMA fragment layout staging -------------------------------------
// flat bf16 index ((ntile*KSTEPS + ks)*64 + lane)*8 + j holds W[k][n],
// k = ks*32 + (lane>>4)*8 + j, n = ntile*16 + (lane&15).
__global__ void stage_w(const float* __restrict__ W1, const float* __restrict__ W2,
                        short* __restrict__ wf1, short* __restrict__ wf2) {
    int t = blockIdx.x * blockDim.x + threadIdx.x;
    if (t < 4096) {                       // W1: 8 ntiles x 8 ksteps x 64 lanes
        int ntile = t >> 9;
        int ks = (t >> 6) & 7;
        int lane = t & 63;
        int h = lane >> 4, c = lane & 15;
#pragma unroll
        for (int j = 0; j < 8; j++) {
            int k = ks * 32 + h * 8 + j;
            wf1[t * 8 + j] = f2bf(W1[k * 128 + ntile * 16 + c]);
        }
    } else if (t < 6144) {                // W2: 8 ntiles x 4 ksteps x 64 lanes
        int s = t - 4096;
        int ntile = s >> 8;
        int ks = (s >> 6) & 3;
        int lane = s & 63;
        int h = lane >> 4, c = lane & 15;
#pragma unroll
        for (int j = 0; j < 8; j++) {
            int k = ks * 32 + h * 8 + j;
            wf2[s * 8 + j] = f2bf(W2[k * 128 + ntile * 16 + c]);
        }
    }
}

// ---- histogram: in-degree count (+ slot index per edge) + weighted degree ---
__global__ void k_hist(const int* __restrict__ ei, const float* __restrict__ w,
                       int* __restrict__ cnt, float* __restrict__ deg,
                       int* __restrict__ slot, int E) {
    for (int i = blockIdx.x * blockDim.x + threadIdx.x; i < E; i += gridDim.x * blockDim.x) {
        int c = ei[E + i];
        slot[i] = atomicAdd(&cnt[c], 1);
        atomicAdd(&deg[c], w[i]);
    }
}

// ---- bucket allocation (wave scan + 1 atomic/wave) + dis = deg^-1/2 --------
__global__ __launch_bounds__(256) void k_alloc(const int* __restrict__ cnt, const float* __restrict__ deg,
                                               float* __restrict__ dis, int* __restrict__ rowstart,
                                               int* __restrict__ gcur, int N) {
    int n = blockIdx.x * blockDim.x + threadIdx.x;
    int lane = threadIdx.x & 63;
    int c = (n < N) ? cnt[n] : 0;
    int v = c;
#pragma unroll
    for (int off = 1; off < 64; off <<= 1) {
        int t = __shfl_up(v, off);
        if (lane >= off) v += t;
    }
    int tot = __shfl(v, 63);
    int base = 0;
    if (lane == 63) base = atomicAdd(gcur, tot);
    base = __shfl(base, 63);
    if (n < N) {
        rowstart[n] = base + v - c;      // exclusive within wave
        float d = deg[n];
        dis[n] = d > 0.f ? rsqrtf(d) : 0.f;
    }
}

// ---- fill CSR buckets (no atomics): (row, norm) pairs per target node -------
__global__ void k_fill(const int* __restrict__ ei, const float* __restrict__ w,
                       const float* __restrict__ dis, const int* __restrict__ rowstart,
                       const int* __restrict__ slot, uint2* __restrict__ ebuf, int E) {
    for (int i = blockIdx.x * blockDim.x + threadIdx.x; i < E; i += gridDim.x * blockDim.x) {
        int r = ei[i], c = ei[E + i];
        float nrm = dis[r] * w[i] * dis[c];
        ebuf[rowstart[c] + slot[i]] = make_uint2((unsigned)r, __float_as_uint(nrm));
    }
}

// ---- MFMA GEMM: hbuf(bf16)[M][128] = bf16(A[M][K] @ W) ----------------------
// AMODE 0: A is f32 row-major. AMODE 2: A is bf16 row-major (direct fragments).
template <int KSTEPS, int AMODE>
__global__ __launch_bounds__(256) void k_gemm(const void* __restrict__ Av,
                                              const short* __restrict__ Wf,
                                              ushort* __restrict__ out, int M) {
    const int lane = threadIdx.x & 63;
    const int wid = threadIdx.x >> 6;
    const int rowbase = blockIdx.x * 64 + wid * 16;
    const int h = lane >> 4, c = lane & 15;
    int arow = rowbase + c;
    if (arow >= M) arow = M - 1;
    const int K = KSTEPS * 32;

    bf16x8 afrag[KSTEPS];
    if (AMODE == 0) {
        const float* arp = (const float*)Av + (long)arow * K + h * 8;
#pragma unroll
        for (int ks = 0; ks < KSTEPS; ks++) {
            float4 a0 = *(const float4*)(arp + ks * 32);
            float4 a1 = *(const float4*)(arp + ks * 32 + 4);
            float v[8] = {a0.x, a0.y, a0.z, a0.w, a1.x, a1.y, a1.z, a1.w};
            bf16x8 f;
#pragma unroll
            for (int j = 0; j < 8; j++) f[j] = f2bf(v[j]);
            afrag[ks] = f;
        }
    } else {
        const ushort* arp = (const ushort*)Av + (long)arow * K + h * 8;
#pragma unroll
        for (int ks = 0; ks < KSTEPS; ks++)
            afrag[ks] = *(const bf16x8*)(arp + ks * 32);
    }

    const bf16x8* wf8 = (const bf16x8*)Wf;
#pragma unroll
    for (int nt = 0; nt < 8; nt++) {
        f32x4 acc = {0.f, 0.f, 0.f, 0.f};
#pragma unroll
        for (int ks = 0; ks < KSTEPS; ks++)
            acc = __builtin_amdgcn_mfma_f32_16x16x32_bf16(afrag[ks], wf8[(nt * KSTEPS + ks) * 64 + lane], acc, 0, 0, 0);
        int orow = rowbase + h * 4;
#pragma unroll
        for (int i = 0; i < 4; i++)
            if (orow + i < M) out[(long)(orow + i) * 128 + nt * 16 + c] = (ushort)f2bf(acc[i]);
    }
}

// ---- gather-aggregate: agg[n] = sum over in-edges of nrm * h[row] -----------
// 8-deep batched loads: one cooperative ebuf load (lanes 0-7), shfl-broadcast,
// then 8 independent row gathers in flight before accumulation.
// FUSE: apply bias+leaky, emit packed bf16 (input for next GEMM). Else f32.
template <bool FUSE>
__global__ __launch_bounds__(256) void k_agg(const uint2* __restrict__ ebuf, const int* __restrict__ rowstart,
                                             const int* __restrict__ cnt, const unsigned* __restrict__ hbuf,
                                             void* __restrict__ outp, const float* __restrict__ bias, int N) {
    int wv = (blockIdx.x * blockDim.x + threadIdx.x) >> 6;
    int lane = threadIdx.x & 63;
    if (wv >= N) return;
    int s = rowstart[wv];
    int m = cnt[wv];
    float ax = 0.f, ay = 0.f;
    for (int base = 0; base < m; base += 8) {
        int rem = m - base;
        int nact = rem < 8 ? rem : 8;
        uint2 p = make_uint2(0u, 0u);            // row 0 / nrm 0 for idle lanes
        if (lane < nact) p = ebuf[s + base + lane];
        int px = (int)p.x, py = (int)p.y;
#pragma unroll
        for (int j = 0; j < 8; j++) {
            unsigned rj = (unsigned)__shfl(px, j);
            float nj = __uint_as_float((unsigned)__shfl(py, j));
            unsigned hv = hbuf[(long)rj * 64 + lane];   // coalesced 256B row gather
            ax = fmaf(nj, __uint_as_float(hv << 16), ax);
            ay = fmaf(nj, __uint_as_float(hv & 0xffff0000u), ay);
        }
    }
    if (FUSE) {
        float2 bv = ((const float2*)bias)[lane];
        float vx = ax + bv.x; vx = vx < 0.f ? SLOPE * vx : vx;
        float vy = ay + bv.y; vy = vy < 0.f ? SLOPE * vy : vy;
        unsigned pk = (unsigned)(ushort)f2bf(vx) | ((unsigned)(ushort)f2bf(vy) << 16);
        ((unsigned*)outp)[(long)wv * 64 + lane] = pk;
    } else {
        ((float2*)outp)[(long)wv * 64 + lane] = make_float2(ax, ay);
    }
}

// ---- pool: per-graph mean of leaky(agg + b2), batch is sorted ---------------
__global__ __launch_bounds__(128) void k_pool(const float* __restrict__ agg, const float* __restrict__ b2,
                                              const int* __restrict__ batch, float* __restrict__ sums,
                                              float* __restrict__ cnts, int N) {
    int n0 = blockIdx.x * 128;
    if (n0 >= N) return;
    int f = threadIdx.x;
    int end = min(n0 + 128, N);
    int curg = batch[n0];
    float acc = 0.f;
    int run = 0;
    float b = b2[f];
    for (int n = n0; n < end; n++) {
        int g = batch[n];
        if (g != curg) {
            atomicAdd(&sums[curg * 128 + f], acc);
            if (f == 0) atomicAdd(&cnts[curg], (float)run);
            acc = 0.f; run = 0; curg = g;
        }
        float v = agg[(long)n * 128 + f] + b;
        v = v < 0.f ? SLOPE * v : v;
        acc += v;
        run++;
    }
    atomicAdd(&sums[curg * 128 + f], acc);
    if (f == 0) atomicAdd(&cnts[curg], (float)run);
}

// ---- classifier + log_softmax ----------------------------------------------
__global__ void k_final(const float* __restrict__ sums, const float* __restrict__ cnts,
                        const float* __restrict__ Wl, const float* __restrict__ bl,
                        float* __restrict__ out, int G) {
    int g = blockIdx.x * blockDim.x + threadIdx.x;
    if (g >= G) return;
    float inv = 1.f / fmaxf(cnts[g], 1.f);
    float l[10];
#pragma unroll
    for (int c = 0; c < 10; c++) l[c] = bl[c];
    for (int k = 0; k < 128; k++) {
        float p = sums[g * 128 + k] * inv;
#pragma unroll
        for (int c = 0; c < 10; c++) l[c] += p * Wl[k * 10 + c];
    }
    float m = l[0];
#pragma unroll
    for (int c = 1; c < 10; c++) m = fmaxf(m, l[c]);
    float s = 0.f;
#pragma unroll
    for (int c = 0; c < 10; c++) s += expf(l[c] - m);
    float lse = m + logf(s);
#pragma unroll
    for (int c = 0; c < 10; c++) out[g * 10 + c] = l[c] - lse;
}

extern "C" void kernel_launch(void* const* d_in, const int* in_sizes, int n_in,
                              void* d_out, int out_size, void* d_ws, size_t ws_size,
                              hipStream_t stream) {
    const float* x  = (const float*)d_in[0];
    const int*   ei = (const int*)d_in[1];
    const float* ew = (const float*)d_in[2];
    const int*   batch = (const int*)d_in[3];
    const float* W1 = (const float*)d_in[4];
    const float* b1 = (const float*)d_in[5];
    const float* W2 = (const float*)d_in[6];
    const float* b2 = (const float*)d_in[7];
    const float* Wl = (const float*)d_in[8];
    const float* bl = (const float*)d_in[9];
    float* out = (float*)d_out;

    const int N = in_sizes[0] / 256;
    const int E = in_sizes[2];
    const int G = out_size / 10;

    char* ws = (char*)d_ws;
    float*  deg      = (float*)(ws);                  // 400,384
    float*  dis      = (float*)(ws + 400384);         // 400,384
    int*    cnt      = (int*)  (ws + 800768);         // 400,384
    int*    rowstart = (int*)  (ws + 1201152);        // 400,384
    int*    gcur     = (int*)  (ws + 1601536);        // 128
    int*    slot     = (int*)  (ws + 1601664);        // 2,400,256
    uint2*  ebuf     = (uint2*)(ws + 4001920);        // 4,800,000
    ushort* hbuf     = (ushort*)(ws + 8801920);       // 25,600,000
    // abuf (bf16 layer-2 input) and agg (f32, layer-2 output) overlap in time
    // only with hbuf; abuf is dead before agg is written -> overlay them.
    ushort* abuf     = (ushort*)(ws + 34401920);      // 25,600,000
    float*  agg      = (float*)(ws + 34401920);       // 51,200,000 (overlays abuf)
    short*  wf1      = (short*)(ws + 85602048);       // 65,536
    short*  wf2      = (short*)(ws + 85667584);       // 32,768
    float*  sums     = (float*)(ws + 85700352);       // 131,072
    float*  cnts     = (float*)(ws + 85831424);       // 1,024

    hipMemsetAsync(deg, 0, (size_t)N * 4, stream);
    hipMemsetAsync(cnt, 0, (size_t)N * 4, stream);
    hipMemsetAsync(gcur, 0, 128, stream);
    hipMemsetAsync(sums, 0, (size_t)G * 128 * 4, stream);
    hipMemsetAsync(cnts, 0, (size_t)G * 4, stream);

    stage_w<<<24, 256, 0, stream>>>(W1, W2, wf1, wf2);
    k_hist<<<1024, 256, 0, stream>>>(ei, ew, cnt, deg, slot, E);
    k_alloc<<<(N + 255) / 256, 256, 0, stream>>>(cnt, deg, dis, rowstart, gcur, N);
    k_fill<<<2048, 256, 0, stream>>>(ei, ew, dis, rowstart, slot, ebuf, E);

    // layer 1: h = bf16(x @ W1); abuf = bf16(leaky(gather-sum + b1))
    k_gemm<8, 0><<<(N + 63) / 64, 256, 0, stream>>>(x, wf1, hbuf, N);
    k_agg<true><<<(N + 3) / 4, 256, 0, stream>>>(ebuf, rowstart, cnt, (const unsigned*)hbuf, abuf, b1, N);

    // layer 2: h = bf16(abuf @ W2); agg = f32 gather-sum
    k_gemm<4, 2><<<(N + 63) / 64, 256, 0, stream>>>(abuf, wf2, hbuf, N);
    k_agg<false><<<(N + 3) / 4, 256, 0, stream>>>(ebuf, rowstart, cnt, (const unsigned*)hbuf, agg, nullptr, N);

    // pool (fused bias2+leaky) + classifier + log_softmax
    k_pool<<<(N + 127) / 128, 128, 0, stream>>>(agg, b2, batch, sums, cnts, N);
    k_final<<<1, 256, 0, stream>>>(sums, cnts, Wl, bl, out, G);
}

// Round 4
// 270.654 us; speedup vs baseline: 4.3311x; 1.0551x over previous
//
#include <hip/hip_runtime.h>

typedef float f32x4 __attribute__((ext_vector_type(4)));
typedef short bf16x8 __attribute__((ext_vector_type(8)));

#define SLOPE 0.01f

__device__ __forceinline__ short f2bf(float f) {
    unsigned int u = __float_as_uint(f);
    unsigned int r = (u + 0x7fffu + ((u >> 16) & 1u)) >> 16;
    return (short)r;
}

// ---- W -> MFMA fragment layout staging -------------------------------------
// flat bf16 index ((ntile*KSTEPS + ks)*64 + lane)*8 + j holds W[k][n],
// k = ks*32 + (lane>>4)*8 + j, n = ntile*16 + (lane&15).
__global__ void stage_w(const float* __restrict__ W1, const float* __restrict__ W2,
                        short* __restrict__ wf1, short* __restrict__ wf2) {
    int t = blockIdx.x * blockDim.x + threadIdx.x;
    if (t < 4096) {                       // W1: 8 ntiles x 8 ksteps x 64 lanes
        int ntile = t >> 9;
        int ks = (t >> 6) & 7;
        int lane = t & 63;
        int h = lane >> 4, c = lane & 15;
#pragma unroll
        for (int j = 0; j < 8; j++) {
            int k = ks * 32 + h * 8 + j;
            wf1[t * 8 + j] = f2bf(W1[k * 128 + ntile * 16 + c]);
        }
    } else if (t < 6144) {                // W2: 8 ntiles x 4 ksteps x 64 lanes
        int s = t - 4096;
        int ntile = s >> 8;
        int ks = (s >> 6) & 3;
        int lane = s & 63;
        int h = lane >> 4, c = lane & 15;
#pragma unroll
        for (int j = 0; j < 8; j++) {
            int k = ks * 32 + h * 8 + j;
            wf2[s * 8 + j] = f2bf(W2[k * 128 + ntile * 16 + c]);
        }
    }
}

// ---- histogram: in-degree count + slot index per edge (1 int atomic) --------
__global__ void k_hist(const int* __restrict__ ei, int* __restrict__ cnt,
                       int* __restrict__ slot, int E) {
    for (int i = blockIdx.x * blockDim.x + threadIdx.x; i < E; i += gridDim.x * blockDim.x) {
        int c = ei[E + i];
        slot[i] = atomicAdd(&cnt[c], 1);
    }
}

// ---- bucket allocation (wave scan + 1 atomic/wave) --------------------------
__global__ __launch_bounds__(256) void k_alloc(const int* __restrict__ cnt, int* __restrict__ rowstart,
                                               int* __restrict__ gcur, int N) {
    int n = blockIdx.x * blockDim.x + threadIdx.x;
    int lane = threadIdx.x & 63;
    int c = (n < N) ? cnt[n] : 0;
    int v = c;
#pragma unroll
    for (int off = 1; off < 64; off <<= 1) {
        int t = __shfl_up(v, off);
        if (lane >= off) v += t;
    }
    int tot = __shfl(v, 63);
    int base = 0;
    if (lane == 63) base = atomicAdd(gcur, tot);
    base = __shfl(base, 63);
    if (n < N) rowstart[n] = base + v - c;      // exclusive within wave
}

// ---- fill CSR buckets (no atomics): (row, raw w) pairs per target node ------
__global__ void k_fill(const int* __restrict__ ei, const float* __restrict__ w,
                       const int* __restrict__ rowstart, const int* __restrict__ slot,
                       uint2* __restrict__ ebuf, int E) {
    for (int i = blockIdx.x * blockDim.x + threadIdx.x; i < E; i += gridDim.x * blockDim.x) {
        int r = ei[i], c = ei[E + i];
        ebuf[rowstart[c] + slot[i]] = make_uint2((unsigned)r, __float_as_uint(w[i]));
    }
}

// ---- per-node weighted degree (bucket sum, no atomics) + dis = deg^-1/2 -----
__global__ void k_degdis(const int* __restrict__ rowstart, const int* __restrict__ cnt,
                         const uint2* __restrict__ ebuf, float* __restrict__ dis, int N) {
    int n = blockIdx.x * blockDim.x + threadIdx.x;
    if (n >= N) return;
    int s = rowstart[n], m = cnt[n];
    float d = 0.f;
    for (int i = 0; i < m; i++) d += __uint_as_float(ebuf[s + i].y);
    dis[n] = d > 0.f ? rsqrtf(d) : 0.f;
}

// ---- MFMA GEMM: hbuf(bf16)[M][128] = bf16(A[M][K] @ W) ----------------------
// AMODE 0: A f32 row-major; AMODE 2: A bf16 row-major (direct fragments).
// Swapped operands: D = mfma(Wfrag, Afrag) -> lane holds row (lane&15),
// 4 consecutive cols ((lane>>4)*4 + i) => one 8B store per ntile per row-group.
template <int KSTEPS, int AMODE>
__global__ __launch_bounds__(256) void k_gemm(const void* __restrict__ Av,
                                              const short* __restrict__ Wf,
                                              ushort* __restrict__ out, int M) {
    const int lane = threadIdx.x & 63;
    const int wid = threadIdx.x >> 6;
    const int h = lane >> 4, c = lane & 15;
    const int rowW = blockIdx.x * 128 + wid * 32;   // this wave's 32 rows
    const int K = KSTEPS * 32;

    bf16x8 afr[2][KSTEPS];
#pragma unroll
    for (int rg = 0; rg < 2; rg++) {
        int arow = rowW + rg * 16 + c;
        if (arow >= M) arow = M - 1;
        if (AMODE == 0) {
            const float* arp = (const float*)Av + (long)arow * K + h * 8;
#pragma unroll
            for (int ks = 0; ks < KSTEPS; ks++) {
                float4 a0 = *(const float4*)(arp + ks * 32);
                float4 a1 = *(const float4*)(arp + ks * 32 + 4);
                bf16x8 f;
                f[0] = f2bf(a0.x); f[1] = f2bf(a0.y); f[2] = f2bf(a0.z); f[3] = f2bf(a0.w);
                f[4] = f2bf(a1.x); f[5] = f2bf(a1.y); f[6] = f2bf(a1.z); f[7] = f2bf(a1.w);
                afr[rg][ks] = f;
            }
        } else {
            const ushort* arp = (const ushort*)Av + (long)arow * K + h * 8;
#pragma unroll
            for (int ks = 0; ks < KSTEPS; ks++)
                afr[rg][ks] = *(const bf16x8*)(arp + ks * 32);
        }
    }

    const bf16x8* wf8 = (const bf16x8*)Wf;
#pragma unroll
    for (int nt = 0; nt < 8; nt++) {        // 8 independent iterations: compiler cross-schedules
        bf16x8 bfr[KSTEPS];
#pragma unroll
        for (int ks = 0; ks < KSTEPS; ks++) bfr[ks] = wf8[(nt * KSTEPS + ks) * 64 + lane];
        f32x4 acc0 = {0.f, 0.f, 0.f, 0.f}, acc1 = {0.f, 0.f, 0.f, 0.f};
#pragma unroll
        for (int ks = 0; ks < KSTEPS; ks++) {
            acc0 = __builtin_amdgcn_mfma_f32_16x16x32_bf16(bfr[ks], afr[0][ks], acc0, 0, 0, 0);
            acc1 = __builtin_amdgcn_mfma_f32_16x16x32_bf16(bfr[ks], afr[1][ks], acc1, 0, 0, 0);
        }
#pragma unroll
        for (int rg = 0; rg < 2; rg++) {
            f32x4 acc = rg ? acc1 : acc0;
            int orow = rowW + rg * 16 + c;
            if (orow < M) {
                ushort4 pk;
                pk.x = (ushort)f2bf(acc[0]); pk.y = (ushort)f2bf(acc[1]);
                pk.z = (ushort)f2bf(acc[2]); pk.w = (ushort)f2bf(acc[3]);
                *(ushort4*)(out + (long)orow * 128 + nt * 16 + h * 4) = pk;
            }
        }
    }
}

// ---- gather-aggregate: agg[n] = sum over in-edges of nrm * h[row] -----------
// 8-deep batched loads; nrm = dis[row]*w*dis[col] computed on the fly
// (dis is L2-resident). FUSE: bias+leaky+bf16-pack for next GEMM; else f32.
template <bool FUSE>
__global__ __launch_bounds__(256) void k_agg(const uint2* __restrict__ ebuf, const int* __restrict__ rowstart,
                                             const int* __restrict__ cnt, const float* __restrict__ dis,
                                             const unsigned* __restrict__ hbuf,
                                             void* __restrict__ outp, const float* __restrict__ bias, int N) {
    int wv = (blockIdx.x * blockDim.x + threadIdx.x) >> 6;
    int lane = threadIdx.x & 63;
    if (wv >= N) return;
    int s = rowstart[wv];
    int m = cnt[wv];
    float discol = dis[wv];
    float ax = 0.f, ay = 0.f;
    for (int base = 0; base < m; base += 8) {
        int rem = m - base;
        int nact = rem < 8 ? rem : 8;
        uint2 p = make_uint2(0u, 0u);
        float dr = 0.f;
        if (lane < nact) { p = ebuf[s + base + lane]; dr = dis[p.x]; }
        float nrmL = dr * __uint_as_float(p.y) * discol;   // 0 for idle lanes
        int px = (int)p.x;
#pragma unroll
        for (int j = 0; j < 8; j++) {
            unsigned rj = (unsigned)__shfl(px, j);
            float nj = __shfl(nrmL, j);
            unsigned hv = hbuf[(long)rj * 64 + lane];   // coalesced 256B row gather
            ax = fmaf(nj, __uint_as_float(hv << 16), ax);
            ay = fmaf(nj, __uint_as_float(hv & 0xffff0000u), ay);
        }
    }
    if (FUSE) {
        float2 bv = ((const float2*)bias)[lane];
        float vx = ax + bv.x; vx = vx < 0.f ? SLOPE * vx : vx;
        float vy = ay + bv.y; vy = vy < 0.f ? SLOPE * vy : vy;
        unsigned pk = (unsigned)(ushort)f2bf(vx) | ((unsigned)(ushort)f2bf(vy) << 16);
        ((unsigned*)outp)[(long)wv * 64 + lane] = pk;
    } else {
        ((float2*)outp)[(long)wv * 64 + lane] = make_float2(ax, ay);
    }
}

// ---- pool: per-graph mean of leaky(agg + b2), batch is sorted ---------------
__global__ __launch_bounds__(128) void k_pool(const float* __restrict__ agg, const float* __restrict__ b2,
                                              const int* __restrict__ batch, float* __restrict__ sums,
                                              float* __restrict__ cnts, int N) {
    int n0 = blockIdx.x * 128;
    if (n0 >= N) return;
    int f = threadIdx.x;
    int end = min(n0 + 128, N);
    int curg = batch[n0];
    float acc = 0.f;
    int run = 0;
    float b = b2[f];
    for (int n = n0; n < end; n++) {
        int g = batch[n];
        if (g != curg) {
            atomicAdd(&sums[curg * 128 + f], acc);
            if (f == 0) atomicAdd(&cnts[curg], (float)run);
            acc = 0.f; run = 0; curg = g;
        }
        float v = agg[(long)n * 128 + f] + b;
        v = v < 0.f ? SLOPE * v : v;
        acc += v;
        run++;
    }
    atomicAdd(&sums[curg * 128 + f], acc);
    if (f == 0) atomicAdd(&cnts[curg], (float)run);
}

// ---- classifier + log_softmax ----------------------------------------------
__global__ void k_final(const float* __restrict__ sums, const float* __restrict__ cnts,
                        const float* __restrict__ Wl, const float* __restrict__ bl,
                        float* __restrict__ out, int G) {
    int g = blockIdx.x * blockDim.x + threadIdx.x;
    if (g >= G) return;
    float inv = 1.f / fmaxf(cnts[g], 1.f);
    float l[10];
#pragma unroll
    for (int c = 0; c < 10; c++) l[c] = bl[c];
    for (int k = 0; k < 128; k++) {
        float p = sums[g * 128 + k] * inv;
#pragma unroll
        for (int c = 0; c < 10; c++) l[c] += p * Wl[k * 10 + c];
    }
    float m = l[0];
#pragma unroll
    for (int c = 1; c < 10; c++) m = fmaxf(m, l[c]);
    float s = 0.f;
#pragma unroll
    for (int c = 0; c < 10; c++) s += expf(l[c] - m);
    float lse = m + logf(s);
#pragma unroll
    for (int c = 0; c < 10; c++) out[g * 10 + c] = l[c] - lse;
}

extern "C" void kernel_launch(void* const* d_in, const int* in_sizes, int n_in,
                              void* d_out, int out_size, void* d_ws, size_t ws_size,
                              hipStream_t stream) {
    const float* x  = (const float*)d_in[0];
    const int*   ei = (const int*)d_in[1];
    const float* ew = (const float*)d_in[2];
    const int*   batch = (const int*)d_in[3];
    const float* W1 = (const float*)d_in[4];
    const float* b1 = (const float*)d_in[5];
    const float* W2 = (const float*)d_in[6];
    const float* b2 = (const float*)d_in[7];
    const float* Wl = (const float*)d_in[8];
    const float* bl = (const float*)d_in[9];
    float* out = (float*)d_out;

    const int N = in_sizes[0] / 256;
    const int E = in_sizes[2];
    const int G = out_size / 10;

    char* ws = (char*)d_ws;
    float*  dis      = (float*)(ws);                  // 400,384
    int*    cnt      = (int*)  (ws + 800768);         // 400,384
    int*    rowstart = (int*)  (ws + 1201152);        // 400,384
    int*    gcur     = (int*)  (ws + 1601536);        // 128
    int*    slot     = (int*)  (ws + 1601664);        // 2,400,256
    uint2*  ebuf     = (uint2*)(ws + 4001920);        // 4,800,000
    ushort* hbuf     = (ushort*)(ws + 8801920);       // 25,600,000
    // abuf (bf16 layer-2 input) and agg (f32 layer-2 output) overlay.
    ushort* abuf     = (ushort*)(ws + 34401920);      // 25,600,000
    float*  agg      = (float*)(ws + 34401920);       // 51,200,000 (overlays abuf)
    short*  wf1      = (short*)(ws + 85602048);       // 65,536
    short*  wf2      = (short*)(ws + 85667584);       // 32,768
    float*  sums     = (float*)(ws + 85700352);       // 131,072
    float*  cnts     = (float*)(ws + 85831424);       // 1,024

    hipMemsetAsync(cnt, 0, (size_t)N * 4, stream);
    hipMemsetAsync(gcur, 0, 128, stream);
    hipMemsetAsync(sums, 0, (size_t)G * 128 * 4, stream);
    hipMemsetAsync(cnts, 0, (size_t)G * 4, stream);

    stage_w<<<24, 256, 0, stream>>>(W1, W2, wf1, wf2);
    k_hist<<<(E + 255) / 256, 256, 0, stream>>>(ei, cnt, slot, E);
    k_alloc<<<(N + 255) / 256, 256, 0, stream>>>(cnt, rowstart, gcur, N);
    k_fill<<<(E + 255) / 256, 256, 0, stream>>>(ei, ew, rowstart, slot, ebuf, E);
    k_degdis<<<(N + 255) / 256, 256, 0, stream>>>(rowstart, cnt, ebuf, dis, N);

    // layer 1: h = bf16(x @ W1); abuf = bf16(leaky(gather-sum + b1))
    k_gemm<8, 0><<<(N + 127) / 128, 256, 0, stream>>>(x, wf1, hbuf, N);
    k_agg<true><<<(N + 3) / 4, 256, 0, stream>>>(ebuf, rowstart, cnt, dis, (const unsigned*)hbuf, abuf, b1, N);

    // layer 2: h = bf16(abuf @ W2); agg = f32 gather-sum
    k_gemm<4, 2><<<(N + 127) / 128, 256, 0, stream>>>(abuf, wf2, hbuf, N);
    k_agg<false><<<(N + 3) / 4, 256, 0, stream>>>(ebuf, rowstart, cnt, dis, (const unsigned*)hbuf, agg, nullptr, N);

    // pool (fused bias2+leaky) + classifier + log_softmax
    k_pool<<<(N + 127) / 128, 128, 0, stream>>>(agg, b2, batch, sums, cnts, N);
    k_final<<<1, 256, 0, stream>>>(sums, cnts, Wl, bl, out, G);
}

// Round 5
// 265.031 us; speedup vs baseline: 4.4230x; 1.0212x over previous
//
#include <hip/hip_runtime.h>

typedef float f32x4 __attribute__((ext_vector_type(4)));
typedef short bf16x8 __attribute__((ext_vector_type(8)));

#define SLOPE 0.01f

__device__ __forceinline__ short f2bf(float f) {
    unsigned int u = __float_as_uint(f);
    unsigned int r = (u + 0x7fffu + ((u >> 16) & 1u)) >> 16;
    return (short)r;
}

// ---- W -> MFMA fragment layout staging -------------------------------------
// flat bf16 index ((ntile*KSTEPS + ks)*64 + lane)*8 + j holds W[k][n],
// k = ks*32 + (lane>>4)*8 + j, n = ntile*16 + (lane&15).
__global__ void stage_w(const float* __restrict__ W1, const float* __restrict__ W2,
                        short* __restrict__ wf1, short* __restrict__ wf2) {
    int t = blockIdx.x * blockDim.x + threadIdx.x;
    if (t < 4096) {                       // W1: 8 ntiles x 8 ksteps x 64 lanes
        int ntile = t >> 9;
        int ks = (t >> 6) & 7;
        int lane = t & 63;
        int h = lane >> 4, c = lane & 15;
#pragma unroll
        for (int j = 0; j < 8; j++) {
            int k = ks * 32 + h * 8 + j;
            wf1[t * 8 + j] = f2bf(W1[k * 128 + ntile * 16 + c]);
        }
    } else if (t < 6144) {                // W2: 8 ntiles x 4 ksteps x 64 lanes
        int s = t - 4096;
        int ntile = s >> 8;
        int ks = (s >> 6) & 3;
        int lane = s & 63;
        int h = lane >> 4, c = lane & 15;
#pragma unroll
        for (int j = 0; j < 8; j++) {
            int k = ks * 32 + h * 8 + j;
            wf2[s * 8 + j] = f2bf(W2[k * 128 + ntile * 16 + c]);
        }
    }
}

// ---- histogram: in-degree count + slot index per edge (1 int atomic) --------
__global__ void k_hist(const int* __restrict__ ei, int* __restrict__ cnt,
                       int* __restrict__ slot, int E) {
    for (int i = blockIdx.x * blockDim.x + threadIdx.x; i < E; i += gridDim.x * blockDim.x) {
        int c = ei[E + i];
        slot[i] = atomicAdd(&cnt[c], 1);
    }
}

// ---- bucket allocation (wave scan + 1 atomic/wave) --------------------------
__global__ __launch_bounds__(256) void k_alloc(const int* __restrict__ cnt, int* __restrict__ rowstart,
                                               int* __restrict__ gcur, int N) {
    int n = blockIdx.x * blockDim.x + threadIdx.x;
    int lane = threadIdx.x & 63;
    int c = (n < N) ? cnt[n] : 0;
    int v = c;
#pragma unroll
    for (int off = 1; off < 64; off <<= 1) {
        int t = __shfl_up(v, off);
        if (lane >= off) v += t;
    }
    int tot = __shfl(v, 63);
    int base = 0;
    if (lane == 63) base = atomicAdd(gcur, tot);
    base = __shfl(base, 63);
    if (n < N) rowstart[n] = base + v - c;      // exclusive within wave
}

// ---- fill CSR buckets (no atomics): (row, raw w) pairs per target node ------
__global__ void k_fill(const int* __restrict__ ei, const float* __restrict__ w,
                       const int* __restrict__ rowstart, const int* __restrict__ slot,
                       uint2* __restrict__ ebuf, int E) {
    for (int i = blockIdx.x * blockDim.x + threadIdx.x; i < E; i += gridDim.x * blockDim.x) {
        int r = ei[i], c = ei[E + i];
        ebuf[rowstart[c] + slot[i]] = make_uint2((unsigned)r, __float_as_uint(w[i]));
    }
}

// ---- per-node weighted degree (bucket sum, no atomics) + dis = deg^-1/2 -----
__global__ void k_degdis(const int* __restrict__ rowstart, const int* __restrict__ cnt,
                         const uint2* __restrict__ ebuf, float* __restrict__ dis, int N) {
    int n = blockIdx.x * blockDim.x + threadIdx.x;
    if (n >= N) return;
    int s = rowstart[n], m = cnt[n];
    float d = 0.f;
    for (int i = 0; i < m; i++) d += __uint_as_float(ebuf[s + i].y);
    dis[n] = d > 0.f ? rsqrtf(d) : 0.f;
}

// ---- MFMA GEMM: hbuf(bf16)[M][128] = bf16(A[M][K] @ W) ----------------------
// AMODE 0: A f32 row-major; AMODE 2: A bf16 row-major (direct fragments).
// Swapped operands: D = mfma(Wfrag, Afrag) -> lane holds row (lane&15),
// 4 consecutive cols ((lane>>4)*4+i) => one 8B store per ntile per row-group.
// B-frags are explicitly double-buffered: n-tile nt+1's loads issue before
// nt's MFMAs so L2 latency hides under the matrix pipe.
template <int KSTEPS, int AMODE>
__global__ __launch_bounds__(256) void k_gemm(const void* __restrict__ Av,
                                              const short* __restrict__ Wf,
                                              ushort* __restrict__ out, int M) {
    const int lane = threadIdx.x & 63;
    const int wid = threadIdx.x >> 6;
    const int h = lane >> 4, c = lane & 15;
    const int rowW = blockIdx.x * 128 + wid * 32;   // this wave's 32 rows
    const int K = KSTEPS * 32;

    bf16x8 afr[2][KSTEPS];
#pragma unroll
    for (int rg = 0; rg < 2; rg++) {
        int arow = rowW + rg * 16 + c;
        if (arow >= M) arow = M - 1;
        if (AMODE == 0) {
            const float* arp = (const float*)Av + (long)arow * K + h * 8;
            float4 atmp[2 * KSTEPS];
#pragma unroll
            for (int ks = 0; ks < KSTEPS; ks++) {       // issue all loads first
                atmp[2 * ks]     = *(const float4*)(arp + ks * 32);
                atmp[2 * ks + 1] = *(const float4*)(arp + ks * 32 + 4);
            }
#pragma unroll
            for (int ks = 0; ks < KSTEPS; ks++) {
                float4 a0 = atmp[2 * ks], a1 = atmp[2 * ks + 1];
                bf16x8 f;
                f[0] = f2bf(a0.x); f[1] = f2bf(a0.y); f[2] = f2bf(a0.z); f[3] = f2bf(a0.w);
                f[4] = f2bf(a1.x); f[5] = f2bf(a1.y); f[6] = f2bf(a1.z); f[7] = f2bf(a1.w);
                afr[rg][ks] = f;
            }
        } else {
            const ushort* arp = (const ushort*)Av + (long)arow * K + h * 8;
#pragma unroll
            for (int ks = 0; ks < KSTEPS; ks++)
                afr[rg][ks] = *(const bf16x8*)(arp + ks * 32);
        }
    }

    const bf16x8* wf8 = (const bf16x8*)Wf;
    bf16x8 bcur[KSTEPS], bnxt[KSTEPS];
#pragma unroll
    for (int ks = 0; ks < KSTEPS; ks++) bcur[ks] = wf8[ks * 64 + lane];

#pragma unroll
    for (int nt = 0; nt < 8; nt++) {
        if (nt < 7) {
#pragma unroll
            for (int ks = 0; ks < KSTEPS; ks++)
                bnxt[ks] = wf8[((nt + 1) * KSTEPS + ks) * 64 + lane];   // prefetch
        }
        f32x4 acc0 = {0.f, 0.f, 0.f, 0.f}, acc1 = {0.f, 0.f, 0.f, 0.f};
#pragma unroll
        for (int ks = 0; ks < KSTEPS; ks++) {
            acc0 = __builtin_amdgcn_mfma_f32_16x16x32_bf16(bcur[ks], afr[0][ks], acc0, 0, 0, 0);
            acc1 = __builtin_amdgcn_mfma_f32_16x16x32_bf16(bcur[ks], afr[1][ks], acc1, 0, 0, 0);
        }
#pragma unroll
        for (int rg = 0; rg < 2; rg++) {
            f32x4 acc = rg ? acc1 : acc0;
            int orow = rowW + rg * 16 + c;
            if (orow < M) {
                ushort4 pk;
                pk.x = (ushort)f2bf(acc[0]); pk.y = (ushort)f2bf(acc[1]);
                pk.z = (ushort)f2bf(acc[2]); pk.w = (ushort)f2bf(acc[3]);
                *(ushort4*)(out + (long)orow * 128 + nt * 16 + h * 4) = pk;
            }
        }
#pragma unroll
        for (int ks = 0; ks < KSTEPS; ks++) bcur[ks] = bnxt[ks];   // reg rename
    }
}

// ---- gather-aggregate: agg[n] = sum over in-edges of nrm * h[row] -----------
// 8-deep batched loads; nrm = dis[row]*w*dis[col] computed on the fly
// (dis is L2-resident). FUSE: bias+leaky+bf16-pack for next GEMM; else f32.
template <bool FUSE>
__global__ __launch_bounds__(256) void k_agg(const uint2* __restrict__ ebuf, const int* __restrict__ rowstart,
                                             const int* __restrict__ cnt, const float* __restrict__ dis,
                                             const unsigned* __restrict__ hbuf,
                                             void* __restrict__ outp, const float* __restrict__ bias, int N) {
    int wv = (blockIdx.x * blockDim.x + threadIdx.x) >> 6;
    int lane = threadIdx.x & 63;
    if (wv >= N) return;
    int s = rowstart[wv];
    int m = cnt[wv];
    float discol = dis[wv];
    float ax = 0.f, ay = 0.f;
    for (int base = 0; base < m; base += 8) {
        int rem = m - base;
        int nact = rem < 8 ? rem : 8;
        uint2 p = make_uint2(0u, 0u);
        float dr = 0.f;
        if (lane < nact) { p = ebuf[s + base + lane]; dr = dis[p.x]; }
        float nrmL = dr * __uint_as_float(p.y) * discol;   // 0 for idle lanes
        int px = (int)p.x;
#pragma unroll
        for (int j = 0; j < 8; j++) {
            unsigned rj = (unsigned)__shfl(px, j);
            float nj = __shfl(nrmL, j);
            unsigned hv = hbuf[(long)rj * 64 + lane];   // coalesced 256B row gather
            ax = fmaf(nj, __uint_as_float(hv << 16), ax);
            ay = fmaf(nj, __uint_as_float(hv & 0xffff0000u), ay);
        }
    }
    if (FUSE) {
        float2 bv = ((const float2*)bias)[lane];
        float vx = ax + bv.x; vx = vx < 0.f ? SLOPE * vx : vx;
        float vy = ay + bv.y; vy = vy < 0.f ? SLOPE * vy : vy;
        unsigned pk = (unsigned)(ushort)f2bf(vx) | ((unsigned)(ushort)f2bf(vy) << 16);
        ((unsigned*)outp)[(long)wv * 64 + lane] = pk;
    } else {
        ((float2*)outp)[(long)wv * 64 + lane] = make_float2(ax, ay);
    }
}

// ---- pool: per-graph mean of leaky(agg + b2), batch is sorted ---------------
__global__ __launch_bounds__(128) void k_pool(const float* __restrict__ agg, const float* __restrict__ b2,
                                              const int* __restrict__ batch, float* __restrict__ sums,
                                              float* __restrict__ cnts, int N) {
    int n0 = blockIdx.x * 128;
    if (n0 >= N) return;
    int f = threadIdx.x;
    int end = min(n0 + 128, N);
    int curg = batch[n0];
    float acc = 0.f;
    int run = 0;
    float b = b2[f];
    for (int n = n0; n < end; n++) {
        int g = batch[n];
        if (g != curg) {
            atomicAdd(&sums[curg * 128 + f], acc);
            if (f == 0) atomicAdd(&cnts[curg], (float)run);
            acc = 0.f; run = 0; curg = g;
        }
        float v = agg[(long)n * 128 + f] + b;
        v = v < 0.f ? SLOPE * v : v;
        acc += v;
        run++;
    }
    atomicAdd(&sums[curg * 128 + f], acc);
    if (f == 0) atomicAdd(&cnts[curg], (float)run);
}

// ---- classifier + log_softmax ----------------------------------------------
__global__ void k_final(const float* __restrict__ sums, const float* __restrict__ cnts,
                        const float* __restrict__ Wl, const float* __restrict__ bl,
                        float* __restrict__ out, int G) {
    int g = blockIdx.x * blockDim.x + threadIdx.x;
    if (g >= G) return;
    float inv = 1.f / fmaxf(cnts[g], 1.f);
    float l[10];
#pragma unroll
    for (int c = 0; c < 10; c++) l[c] = bl[c];
    for (int k = 0; k < 128; k++) {
        float p = sums[g * 128 + k] * inv;
#pragma unroll
        for (int c = 0; c < 10; c++) l[c] += p * Wl[k * 10 + c];
    }
    float m = l[0];
#pragma unroll
    for (int c = 1; c < 10; c++) m = fmaxf(m, l[c]);
    float s = 0.f;
#pragma unroll
    for (int c = 0; c < 10; c++) s += expf(l[c] - m);
    float lse = m + logf(s);
#pragma unroll
    for (int c = 0; c < 10; c++) out[g * 10 + c] = l[c] - lse;
}

extern "C" void kernel_launch(void* const* d_in, const int* in_sizes, int n_in,
                              void* d_out, int out_size, void* d_ws, size_t ws_size,
                              hipStream_t stream) {
    const float* x  = (const float*)d_in[0];
    const int*   ei = (const int*)d_in[1];
    const float* ew = (const float*)d_in[2];
    const int*   batch = (const int*)d_in[3];
    const float* W1 = (const float*)d_in[4];
    const float* b1 = (const float*)d_in[5];
    const float* W2 = (const float*)d_in[6];
    const float* b2 = (const float*)d_in[7];
    const float* Wl = (const float*)d_in[8];
    const float* bl = (const float*)d_in[9];
    float* out = (float*)d_out;

    const int N = in_sizes[0] / 256;
    const int E = in_sizes[2];
    const int G = out_size / 10;

    char* ws = (char*)d_ws;
    float*  dis      = (float*)(ws);                  // 400,384
    int*    cnt      = (int*)  (ws + 800768);         // 400,384
    int*    rowstart = (int*)  (ws + 1201152);        // 400,384
    int*    gcur     = (int*)  (ws + 1601536);        // 128
    int*    slot     = (int*)  (ws + 1601664);        // 2,400,256
    uint2*  ebuf     = (uint2*)(ws + 4001920);        // 4,800,000
    ushort* hbuf     = (ushort*)(ws + 8801920);       // 25,600,000
    // abuf (bf16 layer-2 input) and agg (f32 layer-2 output) overlay.
    ushort* abuf     = (ushort*)(ws + 34401920);      // 25,600,000
    float*  agg      = (float*)(ws + 34401920);       // 51,200,000 (overlays abuf)
    short*  wf1      = (short*)(ws + 85602048);       // 65,536
    short*  wf2      = (short*)(ws + 85667584);       // 32,768
    float*  sums     = (float*)(ws + 85700352);       // 131,072
    float*  cnts     = (float*)(ws + 85831424);       // 1,024

    hipMemsetAsync(cnt, 0, (size_t)N * 4, stream);
    hipMemsetAsync(gcur, 0, 128, stream);
    hipMemsetAsync(sums, 0, (size_t)G * 128 * 4, stream);
    hipMemsetAsync(cnts, 0, (size_t)G * 4, stream);

    stage_w<<<24, 256, 0, stream>>>(W1, W2, wf1, wf2);
    k_hist<<<(E + 255) / 256, 256, 0, stream>>>(ei, cnt, slot, E);
    k_alloc<<<(N + 255) / 256, 256, 0, stream>>>(cnt, rowstart, gcur, N);
    k_fill<<<(E + 255) / 256, 256, 0, stream>>>(ei, ew, rowstart, slot, ebuf, E);
    k_degdis<<<(N + 255) / 256, 256, 0, stream>>>(rowstart, cnt, ebuf, dis, N);

    // layer 1: h = bf16(x @ W1); abuf = bf16(leaky(gather-sum + b1))
    k_gemm<8, 0><<<(N + 127) / 128, 256, 0, stream>>>(x, wf1, hbuf, N);
    k_agg<true><<<(N + 3) / 4, 256, 0, stream>>>(ebuf, rowstart, cnt, dis, (const unsigned*)hbuf, abuf, b1, N);

    // layer 2: h = bf16(abuf @ W2); agg = f32 gather-sum
    k_gemm<4, 2><<<(N + 127) / 128, 256, 0, stream>>>(abuf, wf2, hbuf, N);
    k_agg<false><<<(N + 3) / 4, 256, 0, stream>>>(ebuf, rowstart, cnt, dis, (const unsigned*)hbuf, agg, nullptr, N);

    // pool (fused bias2+leaky) + classifier + log_softmax
    k_pool<<<(N + 127) / 128, 128, 0, stream>>>(agg, b2, batch, sums, cnts, N);
    k_final<<<1, 256, 0, stream>>>(sums, cnts, Wl, bl, out, G);
}

// Round 6
// 256.610 us; speedup vs baseline: 4.5682x; 1.0328x over previous
//
#include <hip/hip_runtime.h>

typedef float f32x4 __attribute__((ext_vector_type(4)));
typedef short bf16x8 __attribute__((ext_vector_type(8)));

#define SLOPE 0.01f

__device__ __forceinline__ short f2bf(float f) {
    unsigned int u = __float_as_uint(f);
    unsigned int r = (u + 0x7fffu + ((u >> 16) & 1u)) >> 16;
    return (short)r;
}

// ---- W -> MFMA fragment layout staging -------------------------------------
// flat bf16 index ((ntile*KSTEPS + ks)*64 + lane)*8 + j holds W[k][n],
// k = ks*32 + (lane>>4)*8 + j, n = ntile*16 + (lane&15).
__global__ void stage_w(const float* __restrict__ W1, const float* __restrict__ W2,
                        short* __restrict__ wf1, short* __restrict__ wf2) {
    int t = blockIdx.x * blockDim.x + threadIdx.x;
    if (t < 4096) {                       // W1: 8 ntiles x 8 ksteps x 64 lanes
        int ntile = t >> 9;
        int ks = (t >> 6) & 7;
        int lane = t & 63;
        int h = lane >> 4, c = lane & 15;
#pragma unroll
        for (int j = 0; j < 8; j++) {
            int k = ks * 32 + h * 8 + j;
            wf1[t * 8 + j] = f2bf(W1[k * 128 + ntile * 16 + c]);
        }
    } else if (t < 6144) {                // W2: 8 ntiles x 4 ksteps x 64 lanes
        int s = t - 4096;
        int ntile = s >> 8;
        int ks = (s >> 6) & 3;
        int lane = s & 63;
        int h = lane >> 4, c = lane & 15;
#pragma unroll
        for (int j = 0; j < 8; j++) {
            int k = ks * 32 + h * 8 + j;
            wf2[s * 8 + j] = f2bf(W2[k * 128 + ntile * 16 + c]);
        }
    }
}

// ---- histogram: in-degree count + slot index per edge (1 int atomic) --------
__global__ void k_hist(const int* __restrict__ ei, int* __restrict__ cnt,
                       int* __restrict__ slot, int E) {
    for (int i = blockIdx.x * blockDim.x + threadIdx.x; i < E; i += gridDim.x * blockDim.x) {
        int c = ei[E + i];
        slot[i] = atomicAdd(&cnt[c], 1);
    }
}

// ---- bucket allocation (wave scan + 1 atomic/wave) --------------------------
__global__ __launch_bounds__(256) void k_alloc(const int* __restrict__ cnt, int* __restrict__ rowstart,
                                               int* __restrict__ gcur, int N) {
    int n = blockIdx.x * blockDim.x + threadIdx.x;
    int lane = threadIdx.x & 63;
    int c = (n < N) ? cnt[n] : 0;
    int v = c;
#pragma unroll
    for (int off = 1; off < 64; off <<= 1) {
        int t = __shfl_up(v, off);
        if (lane >= off) v += t;
    }
    int tot = __shfl(v, 63);
    int base = 0;
    if (lane == 63) base = atomicAdd(gcur, tot);
    base = __shfl(base, 63);
    if (n < N) rowstart[n] = base + v - c;      // exclusive within wave
}

// ---- fill CSR buckets (no atomics): (row, raw w) pairs per target node ------
__global__ void k_fill(const int* __restrict__ ei, const float* __restrict__ w,
                       const int* __restrict__ rowstart, const int* __restrict__ slot,
                       uint2* __restrict__ ebuf, int E) {
    for (int i = blockIdx.x * blockDim.x + threadIdx.x; i < E; i += gridDim.x * blockDim.x) {
        int r = ei[i], c = ei[E + i];
        ebuf[rowstart[c] + slot[i]] = make_uint2((unsigned)r, __float_as_uint(w[i]));
    }
}

// ---- per-node weighted degree (bucket sum, no atomics) + dis = deg^-1/2 -----
__global__ void k_degdis(const int* __restrict__ rowstart, const int* __restrict__ cnt,
                         const uint2* __restrict__ ebuf, float* __restrict__ dis, int N) {
    int n = blockIdx.x * blockDim.x + threadIdx.x;
    if (n >= N) return;
    int s = rowstart[n], m = cnt[n];
    float d = 0.f;
    for (int i = 0; i < m; i++) d += __uint_as_float(ebuf[s + i].y);
    dis[n] = d > 0.f ? rsqrtf(d) : 0.f;
}

// ---- MFMA GEMM: hbuf(bf16)[M][128] = bf16(A[M][K] @ W) ----------------------
// AMODE 0: A f32 row-major; AMODE 2: A bf16 row-major (direct fragments).
// W-fragments staged to LDS once per block (lane-linear layout -> conflict-free
// float4 copy; ds_read_b128 at 16B/lane = free 2-way). MFMA B-operand streams
// from LDS; compiler emits fine-grained lgkmcnt for ds_read->MFMA.
// Swapped operands: D = mfma(Wfrag, Afrag) -> lane&15 = row, 4 regs = 4
// consecutive cols -> one 8B store per ntile per row-group.
template <int KSTEPS, int AMODE>
__global__ __launch_bounds__(256, 2) void k_gemm(const void* __restrict__ Av,
                                                 const short* __restrict__ Wf,
                                                 ushort* __restrict__ out, int M) {
    __shared__ short lds[KSTEPS * 8 * 64 * 8];      // KSTEPS=8: 64 KB, =4: 32 KB
    const int tid = threadIdx.x;
    {
        const float4* wsrc = (const float4*)Wf;
        float4* wdst = (float4*)lds;
#pragma unroll
        for (int i = 0; i < KSTEPS * 2; i++)
            wdst[i * 256 + tid] = wsrc[i * 256 + tid];
    }
    __syncthreads();

    const int lane = tid & 63;
    const int wid = tid >> 6;
    const int h = lane >> 4, c = lane & 15;
    const int rowW = blockIdx.x * 128 + wid * 32;   // this wave's 32 rows
    const int K = KSTEPS * 32;

    bf16x8 afr[2][KSTEPS];
#pragma unroll
    for (int rg = 0; rg < 2; rg++) {
        int arow = rowW + rg * 16 + c;
        if (arow >= M) arow = M - 1;
        if (AMODE == 0) {
            const float* arp = (const float*)Av + (long)arow * K + h * 8;
#pragma unroll
            for (int ks = 0; ks < KSTEPS; ks++) {
                float4 a0 = *(const float4*)(arp + ks * 32);
                float4 a1 = *(const float4*)(arp + ks * 32 + 4);
                bf16x8 f;
                f[0] = f2bf(a0.x); f[1] = f2bf(a0.y); f[2] = f2bf(a0.z); f[3] = f2bf(a0.w);
                f[4] = f2bf(a1.x); f[5] = f2bf(a1.y); f[6] = f2bf(a1.z); f[7] = f2bf(a1.w);
                afr[rg][ks] = f;
            }
        } else {
            const ushort* arp = (const ushort*)Av + (long)arow * K + h * 8;
#pragma unroll
            for (int ks = 0; ks < KSTEPS; ks++)
                afr[rg][ks] = *(const bf16x8*)(arp + ks * 32);
        }
    }

    const bf16x8* lf8 = (const bf16x8*)lds;
#pragma unroll
    for (int nt = 0; nt < 8; nt++) {
        bf16x8 bfr[KSTEPS];
#pragma unroll
        for (int ks = 0; ks < KSTEPS; ks++)
            bfr[ks] = lf8[(nt * KSTEPS + ks) * 64 + lane];      // ds_read_b128
        f32x4 acc0 = {0.f, 0.f, 0.f, 0.f}, acc1 = {0.f, 0.f, 0.f, 0.f};
#pragma unroll
        for (int ks = 0; ks < KSTEPS; ks++) {
            acc0 = __builtin_amdgcn_mfma_f32_16x16x32_bf16(bfr[ks], afr[0][ks], acc0, 0, 0, 0);
            acc1 = __builtin_amdgcn_mfma_f32_16x16x32_bf16(bfr[ks], afr[1][ks], acc1, 0, 0, 0);
        }
#pragma unroll
        for (int rg = 0; rg < 2; rg++) {
            f32x4 acc = rg ? acc1 : acc0;
            int orow = rowW + rg * 16 + c;
            if (orow < M) {
                ushort4 pk;
                pk.x = (ushort)f2bf(acc[0]); pk.y = (ushort)f2bf(acc[1]);
                pk.z = (ushort)f2bf(acc[2]); pk.w = (ushort)f2bf(acc[3]);
                *(ushort4*)(out + (long)orow * 128 + nt * 16 + h * 4) = pk;
            }
        }
    }
}

// ---- gather-aggregate: agg[n] = sum over in-edges of nrm * h[row] -----------
// 8-deep batched loads; nrm = dis[row]*w*dis[col] computed on the fly
// (dis is L2-resident). FUSE: bias+leaky+bf16-pack for next GEMM; else f32.
template <bool FUSE>
__global__ __launch_bounds__(256) void k_agg(const uint2* __restrict__ ebuf, const int* __restrict__ rowstart,
                                             const int* __restrict__ cnt, const float* __restrict__ dis,
                                             const unsigned* __restrict__ hbuf,
                                             void* __restrict__ outp, const float* __restrict__ bias, int N) {
    int wv = (blockIdx.x * blockDim.x + threadIdx.x) >> 6;
    int lane = threadIdx.x & 63;
    if (wv >= N) return;
    int s = rowstart[wv];
    int m = cnt[wv];
    float discol = dis[wv];
    float ax = 0.f, ay = 0.f;
    for (int base = 0; base < m; base += 8) {
        int rem = m - base;
        int nact = rem < 8 ? rem : 8;
        uint2 p = make_uint2(0u, 0u);
        float dr = 0.f;
        if (lane < nact) { p = ebuf[s + base + lane]; dr = dis[p.x]; }
        float nrmL = dr * __uint_as_float(p.y) * discol;   // 0 for idle lanes
        int px = (int)p.x;
#pragma unroll
        for (int j = 0; j < 8; j++) {
            unsigned rj = (unsigned)__shfl(px, j);
            float nj = __shfl(nrmL, j);
            unsigned hv = hbuf[(long)rj * 64 + lane];   // coalesced 256B row gather
            ax = fmaf(nj, __uint_as_float(hv << 16), ax);
            ay = fmaf(nj, __uint_as_float(hv & 0xffff0000u), ay);
        }
    }
    if (FUSE) {
        float2 bv = ((const float2*)bias)[lane];
        float vx = ax + bv.x; vx = vx < 0.f ? SLOPE * vx : vx;
        float vy = ay + bv.y; vy = vy < 0.f ? SLOPE * vy : vy;
        unsigned pk = (unsigned)(ushort)f2bf(vx) | ((unsigned)(ushort)f2bf(vy) << 16);
        ((unsigned*)outp)[(long)wv * 64 + lane] = pk;
    } else {
        ((float2*)outp)[(long)wv * 64 + lane] = make_float2(ax, ay);
    }
}

// ---- pool: per-graph mean of leaky(agg + b2), batch is sorted ---------------
__global__ __launch_bounds__(128) void k_pool(const float* __restrict__ agg, const float* __restrict__ b2,
                                              const int* __restrict__ batch, float* __restrict__ sums,
                                              float* __restrict__ cnts, int N) {
    int n0 = blockIdx.x * 128;
    if (n0 >= N) return;
    int f = threadIdx.x;
    int end = min(n0 + 128, N);
    int curg = batch[n0];
    float acc = 0.f;
    int run = 0;
    float b = b2[f];
    for (int n = n0; n < end; n++) {
        int g = batch[n];
        if (g != curg) {
            atomicAdd(&sums[curg * 128 + f], acc);
            if (f == 0) atomicAdd(&cnts[curg], (float)run);
            acc = 0.f; run = 0; curg = g;
        }
        float v = agg[(long)n * 128 + f] + b;
        v = v < 0.f ? SLOPE * v : v;
        acc += v;
        run++;
    }
    atomicAdd(&sums[curg * 128 + f], acc);
    if (f == 0) atomicAdd(&cnts[curg], (float)run);
}

// ---- classifier + log_softmax ----------------------------------------------
__global__ void k_final(const float* __restrict__ sums, const float* __restrict__ cnts,
                        const float* __restrict__ Wl, const float* __restrict__ bl,
                        float* __restrict__ out, int G) {
    int g = blockIdx.x * blockDim.x + threadIdx.x;
    if (g >= G) return;
    float inv = 1.f / fmaxf(cnts[g], 1.f);
    float l[10];
#pragma unroll
    for (int c = 0; c < 10; c++) l[c] = bl[c];
    for (int k = 0; k < 128; k++) {
        float p = sums[g * 128 + k] * inv;
#pragma unroll
        for (int c = 0; c < 10; c++) l[c] += p * Wl[k * 10 + c];
    }
    float m = l[0];
#pragma unroll
    for (int c = 1; c < 10; c++) m = fmaxf(m, l[c]);
    float s = 0.f;
#pragma unroll
    for (int c = 0; c < 10; c++) s += expf(l[c] - m);
    float lse = m + logf(s);
#pragma unroll
    for (int c = 0; c < 10; c++) out[g * 10 + c] = l[c] - lse;
}

extern "C" void kernel_launch(void* const* d_in, const int* in_sizes, int n_in,
                              void* d_out, int out_size, void* d_ws, size_t ws_size,
                              hipStream_t stream) {
    const float* x  = (const float*)d_in[0];
    const int*   ei = (const int*)d_in[1];
    const float* ew = (const float*)d_in[2];
    const int*   batch = (const int*)d_in[3];
    const float* W1 = (const float*)d_in[4];
    const float* b1 = (const float*)d_in[5];
    const float* W2 = (const float*)d_in[6];
    const float* b2 = (const float*)d_in[7];
    const float* Wl = (const float*)d_in[8];
    const float* bl = (const float*)d_in[9];
    float* out = (float*)d_out;

    const int N = in_sizes[0] / 256;
    const int E = in_sizes[2];
    const int G = out_size / 10;

    char* ws = (char*)d_ws;
    float*  dis      = (float*)(ws);                  // 400,384
    int*    cnt      = (int*)  (ws + 800768);         // 400,384
    int*    rowstart = (int*)  (ws + 1201152);        // 400,384
    int*    gcur     = (int*)  (ws + 1601536);        // 128
    int*    slot     = (int*)  (ws + 1601664);        // 2,400,256
    uint2*  ebuf     = (uint2*)(ws + 4001920);        // 4,800,000
    ushort* hbuf     = (ushort*)(ws + 8801920);       // 25,600,000
    // abuf (bf16 layer-2 input) and agg (f32 layer-2 output) overlay.
    ushort* abuf     = (ushort*)(ws + 34401920);      // 25,600,000
    float*  agg      = (float*)(ws + 34401920);       // 51,200,000 (overlays abuf)
    short*  wf1      = (short*)(ws + 85602048);       // 65,536
    short*  wf2      = (short*)(ws + 85667584);       // 32,768
    float*  sums     = (float*)(ws + 85700352);       // 131,072
    float*  cnts     = (float*)(ws + 85831424);       // 1,024

    hipMemsetAsync(cnt, 0, (size_t)N * 4, stream);
    hipMemsetAsync(gcur, 0, 128, stream);
    hipMemsetAsync(sums, 0, (size_t)G * 128 * 4, stream);
    hipMemsetAsync(cnts, 0, (size_t)G * 4, stream);

    stage_w<<<24, 256, 0, stream>>>(W1, W2, wf1, wf2);
    k_hist<<<(E + 255) / 256, 256, 0, stream>>>(ei, cnt, slot, E);
    k_alloc<<<(N + 255) / 256, 256, 0, stream>>>(cnt, rowstart, gcur, N);
    k_fill<<<(E + 255) / 256, 256, 0, stream>>>(ei, ew, rowstart, slot, ebuf, E);
    k_degdis<<<(N + 255) / 256, 256, 0, stream>>>(rowstart, cnt, ebuf, dis, N);

    // layer 1: h = bf16(x @ W1); abuf = bf16(leaky(gather-sum + b1))
    k_gemm<8, 0><<<(N + 127) / 128, 256, 0, stream>>>(x, wf1, hbuf, N);
    k_agg<true><<<(N + 3) / 4, 256, 0, stream>>>(ebuf, rowstart, cnt, dis, (const unsigned*)hbuf, abuf, b1, N);

    // layer 2: h = bf16(abuf @ W2); agg = f32 gather-sum
    k_gemm<4, 2><<<(N + 127) / 128, 256, 0, stream>>>(abuf, wf2, hbuf, N);
    k_agg<false><<<(N + 3) / 4, 256, 0, stream>>>(ebuf, rowstart, cnt, dis, (const unsigned*)hbuf, agg, nullptr, N);

    // pool (fused bias2+leaky) + classifier + log_softmax
    k_pool<<<(N + 127) / 128, 128, 0, stream>>>(agg, b2, batch, sums, cnts, N);
    k_final<<<1, 256, 0, stream>>>(sums, cnts, Wl, bl, out, G);
}